// Round 1
// 350.504 us; speedup vs baseline: 1.1873x; 1.1873x over previous
//
#include <hip/hip_runtime.h>
#include <cstdint>
#include <cstddef>

#define D_MODEL 2048
#define T_SEQ   2048
#define BATCH   2
#define N_HEADS 16
#define KV_HEADS 4
#define HEAD_DIM 128
#define QKV_N   3072          // D_MODEL + 2*512
#define ROWS    (BATCH * T_SEQ) // 4096

typedef float  floatx4 __attribute__((ext_vector_type(4)));
typedef short  shortx8 __attribute__((ext_vector_type(8)));
typedef __bf16 bf16x8  __attribute__((ext_vector_type(8)));

typedef const void __attribute__((address_space(1))) gvoid_t;
typedef void __attribute__((address_space(3)))       svoid_t;

__device__ __forceinline__ floatx4 mfma16(shortx8 a, shortx8 b, floatx4 c) {
  return __builtin_amdgcn_mfma_f32_16x16x32_bf16(
      __builtin_bit_cast(bf16x8, a), __builtin_bit_cast(bf16x8, b), c, 0, 0, 0);
}

__device__ __forceinline__ unsigned short f2bf(float f) {
  union { float f; unsigned int u; } v; v.f = f;
  unsigned int u = v.u;
  u += 0x7fffu + ((u >> 16) & 1u);   // RNE
  return (unsigned short)(u >> 16);
}

// ---------------- fp32 -> bf16 elementwise (x) ----------------
__global__ void cvt_x(const float* __restrict__ in, unsigned short* __restrict__ out, int n4) {
  int i = blockIdx.x * blockDim.x + threadIdx.x;
  if (i >= n4) return;
  float4 v = ((const float4*)in)[i];
  ushort4 o;
  o.x = f2bf(v.x); o.y = f2bf(v.y); o.z = f2bf(v.z); o.w = f2bf(v.w);
  ((ushort4*)out)[i] = o;
}

// ---------------- fp32 W[K][N] -> bf16 Wt[N][K] ----------------
__global__ void transpose_cvt(const float* __restrict__ W, unsigned short* __restrict__ Wt,
                              int K, int N) {
  __shared__ float tile[32][33];
  int n0 = blockIdx.x * 32, k0 = blockIdx.y * 32;
  int tx = threadIdx.x, ty = threadIdx.y;   // (32, 8)
  #pragma unroll
  for (int i = 0; i < 32; i += 8)
    tile[ty + i][tx] = W[(size_t)(k0 + ty + i) * N + n0 + tx];
  __syncthreads();
  #pragma unroll
  for (int i = 0; i < 32; i += 8)
    Wt[(size_t)(n0 + ty + i) * K + k0 + tx] = f2bf(tile[tx][ty + i]);
}

// ---------------- K slice of qkv -> k_staged [b][kvh][d8][t][8] ----------------
__global__ void build_kt(const unsigned short* __restrict__ qkv, unsigned short* __restrict__ kst) {
  int o = blockIdx.x * blockDim.x + threadIdx.x;   // (((b*4+kvh)*16+d8)*2048 + t)
  int t   = o & 2047;
  int d8  = (o >> 11) & 15;
  int kvh = (o >> 15) & 3;
  int b   = o >> 17;
  uint4 v = *(const uint4*)(qkv + (size_t)(b * T_SEQ + t) * QKV_N
                            + D_MODEL + kvh * HEAD_DIM + d8 * 8);
  *(uint4*)(kst + (size_t)o * 8) = v;
}

// ---------------- V slice of qkv -> v_staged [b][kvh][t8][d][8] ----------------
__global__ void build_vt(const unsigned short* __restrict__ qkv, unsigned short* __restrict__ vst) {
  int o = blockIdx.x * blockDim.x + threadIdx.x;   // (((b*4+kvh)*256+t8)*128 + d)
  int d   = o & 127;
  int t8  = (o >> 7) & 255;
  int kvh = (o >> 15) & 3;
  int b   = o >> 17;
  const unsigned short* src = qkv + (size_t)(b * T_SEQ + t8 * 8) * QKV_N
                              + D_MODEL + 512 + kvh * HEAD_DIM + d;
  union { unsigned short s[8]; uint4 v; } tmp;
  #pragma unroll
  for (int j = 0; j < 8; ++j) tmp.s[j] = src[(size_t)j * QKV_N];
  *(uint4*)(vst + (size_t)o * 8) = tmp.v;
}

// ---------------- 256x256 8-phase bf16 GEMM: C = A[M][K] * Bt[N][K]^T + bias ----
// 512 threads (8 waves, 2x4). Per wave: 2x2 chunks of 64x32 output, one chunk in
// each (A-half, B-half) pair so each phase touches exactly one half-tile pair.
// LDS 128 KiB: 2 dbuf x 2 half x 128x64 x {A,B}. Counted vmcnt(6), XOR swizzle.
__global__ __launch_bounds__(512, 2) void gemm256(
    const unsigned short* __restrict__ A,
    const unsigned short* __restrict__ Bt,
    const float* __restrict__ bias,
    void* __restrict__ Cout,
    int M, int N, int K, int c_bf16)
{
  __shared__ __align__(16) unsigned short lds[65536];  // A: [0,32768), B: [32768,65536)
  const int tid  = threadIdx.x;
  const int wave = tid >> 6, lane = tid & 63;
  const int quad = lane >> 4, l16 = lane & 15;
  const int wr = wave >> 2, wc = wave & 3;        // 2 x 4 wave grid
  const int bm = blockIdx.y * 256, bn = blockIdx.x * 256;
  const int NT = K >> 6;                          // 64-wide K tiles

  // ---- staging addressing (inverse-swizzled global source, linear LDS dest) ----
  const int r0 = tid >> 3;                        // row 0..63 (j=0); +64 for j=1
  const int cx = (tid & 7) ^ (r0 & 7);            // inverse swizzle of k-chunk
  const size_t K64 = (size_t)64 * K;              // 64 rows worth of elements
  const unsigned short* a_src = A  + (size_t)(bm + r0) * K + cx * 8;
  const unsigned short* b_src = Bt + (size_t)(bn + r0) * K + cx * 8;
  const int wOff = wave * 512;                    // wave-uniform LDS offset (elems)

  #define LDSA_(buf, half) (lds + (((buf) << 1) + (half)) * 8192)
  #define LDSB_(buf, half) (lds + 32768 + (((buf) << 1) + (half)) * 8192)
  #define KOFF(h, t) ((size_t)(h) * 128 * K + (size_t)(t) * 64)
  #define STAGE(srcbase, ldshalf, koff) do {                                          \
    __builtin_amdgcn_global_load_lds((gvoid_t*)((srcbase) + (koff)),                  \
        (svoid_t*)((ldshalf) + wOff), 16, 0, 0);                                      \
    __builtin_amdgcn_global_load_lds((gvoid_t*)((srcbase) + (koff) + K64),            \
        (svoid_t*)((ldshalf) + wOff + 4096), 16, 0, 0);                               \
  } while (0)

  // ---- fragment read addressing (swizzled) ----
  const int rowA = (wr * 64 + l16) * 64;          // within half-tile, elems
  const int rowB = (wc * 32 + l16) * 64;
  const int xo0 = ((quad)     ^ (l16 & 7)) * 8;   // ks=0 chunk
  const int xo1 = ((4 + quad) ^ (l16 & 7)) * 8;   // ks=1 chunk

  floatx4 acc[8][4] = {};
  shortx8 Afr[4][2];   // current A-half fragments (mi 0-3 x ks)
  shortx8 Bfr[4][2];   // all B fragments (ni 0-3 x ks), resident whole tile

  // ---- prologue: A0(0), B0(0), B1(0), A1(0), A0(1), B0(1), B1(1) ----
  STAGE(a_src, LDSA_(0, 0), KOFF(0, 0));
  STAGE(b_src, LDSB_(0, 0), KOFF(0, 0));
  STAGE(b_src, LDSB_(0, 1), KOFF(1, 0));
  STAGE(a_src, LDSA_(0, 1), KOFF(1, 0));
  if (NT > 1) {
    STAGE(a_src, LDSA_(1, 0), KOFF(0, 1));
    STAGE(b_src, LDSB_(1, 0), KOFF(0, 1));
    STAGE(b_src, LDSB_(1, 1), KOFF(1, 1));
  }

  for (int t = 0; t < NT; ++t) {
    const int buf = t & 1;
    unsigned short* sA0 = LDSA_(buf, 0);
    unsigned short* sA1 = LDSA_(buf, 1);
    unsigned short* sB0 = LDSB_(buf, 0);
    unsigned short* sB1 = LDSB_(buf, 1);

    // ---- phase 0: Q(0,0) ----
    if (t == NT - 1) asm volatile("s_waitcnt vmcnt(0)" ::: "memory");
    else             asm volatile("s_waitcnt vmcnt(6)" ::: "memory");
    __builtin_amdgcn_s_barrier();
    #pragma unroll
    for (int mi = 0; mi < 4; ++mi) {
      Afr[mi][0] = *(const shortx8*)(sA0 + rowA + mi * 1024 + xo0);
      Afr[mi][1] = *(const shortx8*)(sA0 + rowA + mi * 1024 + xo1);
    }
    #pragma unroll
    for (int ni = 0; ni < 2; ++ni) {
      Bfr[ni][0] = *(const shortx8*)(sB0 + rowB + ni * 1024 + xo0);
      Bfr[ni][1] = *(const shortx8*)(sB0 + rowB + ni * 1024 + xo1);
    }
    if (t + 1 < NT) STAGE(a_src, LDSA_(buf ^ 1, 1), KOFF(1, t + 1));
    asm volatile("s_waitcnt lgkmcnt(0)" ::: "memory");
    __builtin_amdgcn_s_setprio(1);
    #pragma unroll
    for (int ks = 0; ks < 2; ++ks)
      #pragma unroll
      for (int mi = 0; mi < 4; ++mi)
        #pragma unroll
        for (int ni = 0; ni < 2; ++ni)
          acc[mi][ni] = mfma16(Afr[mi][ks], Bfr[ni][ks], acc[mi][ni]);
    __builtin_amdgcn_s_setprio(0);
    __builtin_amdgcn_s_barrier();

    // ---- phase 1: Q(0,1) ----
    #pragma unroll
    for (int ni = 0; ni < 2; ++ni) {
      Bfr[2 + ni][0] = *(const shortx8*)(sB1 + rowB + ni * 1024 + xo0);
      Bfr[2 + ni][1] = *(const shortx8*)(sB1 + rowB + ni * 1024 + xo1);
    }
    if (t + 2 < NT) STAGE(a_src, LDSA_(buf, 0), KOFF(0, t + 2));
    __builtin_amdgcn_s_barrier();
    asm volatile("s_waitcnt lgkmcnt(0)" ::: "memory");
    __builtin_amdgcn_s_setprio(1);
    #pragma unroll
    for (int ks = 0; ks < 2; ++ks)
      #pragma unroll
      for (int mi = 0; mi < 4; ++mi)
        #pragma unroll
        for (int ni = 0; ni < 2; ++ni)
          acc[mi][2 + ni] = mfma16(Afr[mi][ks], Bfr[2 + ni][ks], acc[mi][2 + ni]);
    __builtin_amdgcn_s_setprio(0);
    __builtin_amdgcn_s_barrier();

    // ---- phase 2: Q(1,1) ----
    #pragma unroll
    for (int mi = 0; mi < 4; ++mi) {
      Afr[mi][0] = *(const shortx8*)(sA1 + rowA + mi * 1024 + xo0);
      Afr[mi][1] = *(const shortx8*)(sA1 + rowA + mi * 1024 + xo1);
    }
    if (t + 2 < NT) STAGE(b_src, LDSB_(buf, 0), KOFF(0, t + 2));
    __builtin_amdgcn_s_barrier();
    asm volatile("s_waitcnt lgkmcnt(0)" ::: "memory");
    __builtin_amdgcn_s_setprio(1);
    #pragma unroll
    for (int ks = 0; ks < 2; ++ks)
      #pragma unroll
      for (int mi = 0; mi < 4; ++mi)
        #pragma unroll
        for (int ni = 0; ni < 2; ++ni)
          acc[4 + mi][2 + ni] = mfma16(Afr[mi][ks], Bfr[2 + ni][ks], acc[4 + mi][2 + ni]);
    __builtin_amdgcn_s_setprio(0);
    __builtin_amdgcn_s_barrier();

    // ---- phase 3: Q(1,0) ----
    if (t + 2 < NT) STAGE(b_src, LDSB_(buf, 1), KOFF(1, t + 2));
    __builtin_amdgcn_s_barrier();
    __builtin_amdgcn_s_setprio(1);
    #pragma unroll
    for (int ks = 0; ks < 2; ++ks)
      #pragma unroll
      for (int mi = 0; mi < 4; ++mi)
        #pragma unroll
        for (int ni = 0; ni < 2; ++ni)
          acc[4 + mi][ni] = mfma16(Afr[mi][ks], Bfr[ni][ks], acc[4 + mi][ni]);
    __builtin_amdgcn_s_setprio(0);
    __builtin_amdgcn_s_barrier();
  }

  // ---- epilogue ----
  #pragma unroll
  for (int mi = 0; mi < 8; ++mi) {
    const int row = bm + (mi >> 2) * 128 + wr * 64 + (mi & 3) * 16 + quad * 4;
    #pragma unroll
    for (int ni = 0; ni < 4; ++ni) {
      const int col = bn + (ni >> 1) * 128 + wc * 32 + (ni & 1) * 16 + l16;
      const float bv = bias[col];
      #pragma unroll
      for (int r = 0; r < 4; ++r) {
        float v = acc[mi][ni][r] + bv;
        if (c_bf16)
          ((unsigned short*)Cout)[(size_t)(row + r) * N + col] = f2bf(v);
        else
          ((float*)Cout)[(size_t)(row + r) * N + col] = v;
      }
    }
  }
  #undef LDSA_
  #undef LDSB_
  #undef KOFF
  #undef STAGE
}

// ---------------- flash attention, GQA, causal — uniform-cost blocks ----------------
__global__ __launch_bounds__(256) void attn_kernel(
    const unsigned short* __restrict__ qkv,   // (B*T, 3072) bf16 (for Q)
    const unsigned short* __restrict__ kst,   // [b][kvh][d8][t][8]
    const unsigned short* __restrict__ vst,   // [b][kvh][t8][d][8]
    unsigned short* __restrict__ aout)        // (B*T, D_MODEL) bf16
{
  __shared__ __align__(16) unsigned short sK[16 * 64 * 8];   // [d8][key][8]
  __shared__ __align__(16) unsigned short sV[8 * 128 * 8];   // [t8][d][8]
  __shared__ __align__(16) unsigned short sP[4][8 * 16 * 8]; // per-wave [k8][row][8]

  const int tid  = threadIdx.x;
  const int wave = tid >> 6, lane = tid & 63;
  const int quad = lane >> 4, l16 = lane & 15;
  const int head = blockIdx.y, b = blockIdx.z;
  const int kvh = head >> 2;
  const float cf = 0.08838834764831845f * 1.4426950408889634f;  // scale*log2e

  const unsigned short* kbase = kst + (size_t)((b * KV_HEADS + kvh) * 16) * 2048 * 8;
  const unsigned short* vbase = vst + (size_t)((b * KV_HEADS + kvh) * 256) * 128 * 8;
  unsigned short* sPw = sP[wave];

  #pragma unroll 1
  for (int half = 0; half < 2; ++half) {
    const int qt = half ? blockIdx.x : (31 - blockIdx.x);
    const int q0 = qt * 64;

    shortx8 qf[4];
    {
      const unsigned short* qp = qkv + (size_t)(b * T_SEQ + q0 + wave * 16 + l16) * QKV_N
                                 + head * HEAD_DIM + quad * 8;
      #pragma unroll
      for (int ks = 0; ks < 4; ++ks)
        qf[ks] = *(const shortx8*)(qp + ks * 32);
    }

    float m_i[4], l_i[4];
    #pragma unroll
    for (int r = 0; r < 4; ++r) { m_i[r] = -__builtin_inff(); l_i[r] = 0.f; }
    floatx4 o_acc[8] = {};

    for (int kt = 0; kt <= qt; ++kt) {
      const int kb = kt * 64;

      __syncthreads();   // A: all waves done reading the previous tile
      #pragma unroll
      for (int it = 0; it < 4; ++it) {
        const int c = it * 4 + wave;
        __builtin_amdgcn_global_load_lds(
            (gvoid_t*)(kbase + ((size_t)c * 2048 + kb) * 8 + lane * 8),
            (svoid_t*)(sK + c * 512), 16, 0, 0);
      }
      const unsigned short* vtile = vbase + (size_t)(kb >> 3) * 128 * 8;
      #pragma unroll
      for (int it = 0; it < 4; ++it) {
        const int c = it * 4 + wave;
        __builtin_amdgcn_global_load_lds(
            (gvoid_t*)(vtile + c * 512 + lane * 8),
            (svoid_t*)(sV + c * 512), 16, 0, 0);
      }
      __syncthreads();   // B: tile visible

      floatx4 s[4] = {};
      #pragma unroll
      for (int ks = 0; ks < 4; ++ks) {
        #pragma unroll
        for (int ct = 0; ct < 4; ++ct) {
          shortx8 kf = *(const shortx8*)&sK[((ks * 4 + quad) * 64 + ct * 16 + l16) * 8];
          s[ct] = mfma16(qf[ks], kf, s[ct]);
        }
      }

      if (kt == qt) {
        const int qrow = q0 + wave * 16 + quad * 4;
        #pragma unroll
        for (int ct = 0; ct < 4; ++ct) {
          const int kcol = kb + ct * 16 + l16;
          #pragma unroll
          for (int r = 0; r < 4; ++r)
            if (kcol > qrow + r) s[ct][r] = -__builtin_inff();
        }
      }

      float alpha_r[4];
      #pragma unroll
      for (int r = 0; r < 4; ++r) {
        float mx = fmaxf(fmaxf(s[0][r], s[1][r]), fmaxf(s[2][r], s[3][r]));
        mx = fmaxf(mx, __shfl_xor(mx, 1));
        mx = fmaxf(mx, __shfl_xor(mx, 2));
        mx = fmaxf(mx, __shfl_xor(mx, 4));
        mx = fmaxf(mx, __shfl_xor(mx, 8));
        const float newm = fmaxf(m_i[r], mx);
        const float nmc = newm * cf;
        float p0 = exp2f(fmaf(s[0][r], cf, -nmc));
        float p1 = exp2f(fmaf(s[1][r], cf, -nmc));
        float p2 = exp2f(fmaf(s[2][r], cf, -nmc));
        float p3 = exp2f(fmaf(s[3][r], cf, -nmc));
        s[0][r] = p0; s[1][r] = p1; s[2][r] = p2; s[3][r] = p3;
        const float alpha = exp2f(fmaf(m_i[r], cf, -nmc));
        alpha_r[r] = alpha;
        l_i[r] = l_i[r] * alpha + ((p0 + p1) + (p2 + p3));
        m_i[r] = newm;
      }
      if (__ballot(alpha_r[0] < 1.f || alpha_r[1] < 1.f ||
                   alpha_r[2] < 1.f || alpha_r[3] < 1.f)) {
        #pragma unroll
        for (int nt = 0; nt < 8; ++nt)
          #pragma unroll
          for (int r = 0; r < 4; ++r) o_acc[nt][r] *= alpha_r[r];
      }

      #pragma unroll
      for (int ct = 0; ct < 4; ++ct)
        #pragma unroll
        for (int r = 0; r < 4; ++r)
          sPw[((ct * 2 + (l16 >> 3)) * 16 + quad * 4 + r) * 8 + (l16 & 7)] = f2bf(s[ct][r]);
      __asm__ __volatile__("s_waitcnt lgkmcnt(0)" ::: "memory");

      #pragma unroll
      for (int ks = 0; ks < 2; ++ks) {
        shortx8 pf = *(const shortx8*)&sPw[((ks * 4 + quad) * 16 + l16) * 8];
        #pragma unroll
        for (int nt = 0; nt < 8; ++nt) {
          shortx8 vf = *(const shortx8*)&sV[((ks * 4 + quad) * 128 + nt * 16 + l16) * 8];
          o_acc[nt] = mfma16(pf, vf, o_acc[nt]);
        }
      }
    }

    const int trow = q0 + wave * 16 + quad * 4;
    #pragma unroll
    for (int r = 0; r < 4; ++r) {
      float l = l_i[r];
      l += __shfl_xor(l, 1);
      l += __shfl_xor(l, 2);
      l += __shfl_xor(l, 4);
      l += __shfl_xor(l, 8);
      const float inv = 1.f / l;
      #pragma unroll
      for (int nt = 0; nt < 8; ++nt) {
        aout[(size_t)(b * T_SEQ + trow + r) * D_MODEL + head * HEAD_DIM + nt * 16 + l16] =
            f2bf(o_acc[nt][r] * inv);
      }
    }
  }
}

extern "C" void kernel_launch(void* const* d_in, const int* in_sizes, int n_in,
                              void* d_out, int out_size, void* d_ws, size_t ws_size,
                              hipStream_t stream) {
  const float* x      = (const float*)d_in[0];
  // d_in[1] = attn_mask (causal; unused)
  const float* qkv_w  = (const float*)d_in[2];
  const float* qkv_b  = (const float*)d_in[3];
  const float* proj_w = (const float*)d_in[4];
  const float* proj_b = (const float*)d_in[5];
  float* out = (float*)d_out;

  char* ws = (char*)d_ws;
  unsigned short* x_bf    = (unsigned short*)(ws);
  unsigned short* qkvw_t  = (unsigned short*)(ws + (size_t)16777216);
  unsigned short* projw_t = (unsigned short*)(ws + (size_t)29360128);
  unsigned short* qkvbuf  = (unsigned short*)(ws + (size_t)37748736);
  unsigned short* vstaged = (unsigned short*)(ws + (size_t)62914560);
  unsigned short* kstaged = qkvw_t;  // safe alias: qkvw_t dead after GEMM1
  unsigned short* attn_out = x_bf;   // safe alias: x_bf dead after GEMM1

  cvt_x<<<(ROWS * D_MODEL / 4 + 255) / 256, 256, 0, stream>>>(x, x_bf, ROWS * D_MODEL / 4);
  transpose_cvt<<<dim3(QKV_N / 32, D_MODEL / 32), dim3(32, 8), 0, stream>>>(qkv_w, qkvw_t, D_MODEL, QKV_N);
  transpose_cvt<<<dim3(D_MODEL / 32, D_MODEL / 32), dim3(32, 8), 0, stream>>>(proj_w, projw_t, D_MODEL, D_MODEL);
  gemm256<<<dim3(QKV_N / 256, ROWS / 256), 512, 0, stream>>>(
      x_bf, qkvw_t, qkv_b, (void*)qkvbuf, ROWS, QKV_N, D_MODEL, 1);
  build_kt<<<1024, 256, 0, stream>>>(qkvbuf, kstaged);
  build_vt<<<1024, 256, 0, stream>>>(qkvbuf, vstaged);
  attn_kernel<<<dim3(16, N_HEADS, BATCH), 256, 0, stream>>>(qkvbuf, kstaged, vstaged, attn_out);
  gemm256<<<dim3(D_MODEL / 256, ROWS / 256), 512, 0, stream>>>(
      attn_out, projw_t, proj_b, (void*)out, ROWS, D_MODEL, D_MODEL, 0);
}